// Round 8
// baseline (24.057 us; speedup 1.0000x reference)
//
#include <hip/hip_runtime.h>

// color_entropy_loss: x [32,3,512,512] f32 -> scalar f32
//   temp = (x*255).mean(axis=1); idx = clip(int(temp),0,255)
//   per-batch 256-bin histogram; hist[0] forced to H*W; hist += 1
//   prob = hist/(H*W+256); loss = mean_b( sum(prob*log(prob)) )
//
// R8: R7 minus nontemporal loads (A/B: nt bypasses L2 burst-staging on
// streaming reads and may cap read BW; writes like fillBuffer hit 7 TB/s
// through L2). Everything else identical to R7 (22.14 us).

typedef float vfloat4 __attribute__((ext_vector_type(4)));

constexpr int BATCH = 32;
constexpr int HW_ = 512 * 512;      // 262144
constexpr int BINS = 256;
constexpr int THREADS = 256;
constexpr int BPB = 64;                                   // blocks per batch -> 2048 blocks
constexpr int GROUPS_PER_BLOCK = (HW_ / 4) / BPB;         // 1024 float4 groups
constexpr int GPT = GROUPS_PER_BLOCK / THREADS;           // 4 groups per thread
constexpr int UNROLL = 4;
constexpr int PASSES = GPT / UNROLL;                      // 1

__global__ __launch_bounds__(THREADS) void hist_kernel(const float* __restrict__ x,
                                                       unsigned short* __restrict__ ws,
                                                       float* __restrict__ out) {
    // Per-wave privatized histograms: 4 waves * 256 bins * 4B = 4 KiB LDS
    __shared__ unsigned lh[4][BINS];
    const int t = threadIdx.x;
    const int wave = t >> 6;
#pragma unroll
    for (int w = 0; w < 4; ++w) lh[w][t] = 0u;
    if (blockIdx.x == 0 && blockIdx.y == 0 && t == 0) out[0] = 0.0f;  // K2 accumulates
    __syncthreads();

    const int b = blockIdx.y;
    const float* base = x + (size_t)b * 3 * HW_;
    const vfloat4* __restrict__ p0 = (const vfloat4*)(base);
    const vfloat4* __restrict__ p1 = (const vfloat4*)(base + HW_);
    const vfloat4* __restrict__ p2 = (const vfloat4*)(base + 2 * HW_);
    const int g0 = blockIdx.x * GROUPS_PER_BLOCK + t;

#pragma unroll
    for (int pass = 0; pass < PASSES; ++pass) {
        vfloat4 A[UNROLL], Bc[UNROLL], Cc[UNROLL];
#pragma unroll
        for (int u = 0; u < UNROLL; ++u) {
            int g = g0 + (pass * UNROLL + u) * THREADS;
            A[u]  = p0[g];
            Bc[u] = p1[g];
            Cc[u] = p2[g];
        }
#pragma unroll
        for (int u = 0; u < UNROLL; ++u) {
            // mean(x*255) = (a+b+c)*85 up to rounding; bin flips only at
            // integer boundaries (~1e-5 loss effect per flip, thr=0.103)
            float t0 = ((A[u].x + Bc[u].x) + Cc[u].x) * 85.0f;
            float t1 = ((A[u].y + Bc[u].y) + Cc[u].y) * 85.0f;
            float t2 = ((A[u].z + Bc[u].z) + Cc[u].z) * 85.0f;
            float t3 = ((A[u].w + Bc[u].w) + Cc[u].w) * 85.0f;
            int i0 = min(max((int)t0, 0), 255);   // trunc == astype(int32)
            int i1 = min(max((int)t1, 0), 255);
            int i2 = min(max((int)t2, 0), 255);
            int i3 = min(max((int)t3, 0), 255);
            atomicAdd(&lh[wave][i0], 1u);
            atomicAdd(&lh[wave][i1], 1u);
            atomicAdd(&lh[wave][i2], 1u);
            atomicAdd(&lh[wave][i3], 1u);
        }
    }
    __syncthreads();
    // Non-atomic per-block u16 partial store (max count 4096/block fits u16;
    // every slot written every call -> no zeroing needed)
    unsigned total = lh[0][t] + lh[1][t] + lh[2][t] + lh[3][t];
    ws[((size_t)(b * BPB + blockIdx.x)) * BINS + t] = (unsigned short)total;
}

__global__ __launch_bounds__(256) void entropy_kernel(const unsigned short* __restrict__ ws,
                                                      float* __restrict__ out) {
    const int t = threadIdx.x;
    const int b = blockIdx.x;
    unsigned cnt = 0;
#pragma unroll 8
    for (int blk = 0; blk < BPB; ++blk)
        cnt += ws[((size_t)(b * BPB + blk)) * BINS + t];   // coalesced 128B/wave

    const float inv_np = 1.0f / (float)(HW_ + BINS);       // 1/262400
    // bin-0 quirk: counts[:,0] = H*W, then +1 smoothing on every bin
    float hist = (t == 0) ? ((float)HW_ + 1.0f) : ((float)cnt + 1.0f);
    float p = hist * inv_np;
    float v = p * logf(p);

    __shared__ float red[256];
    red[t] = v;
    __syncthreads();
    for (int off = 128; off > 0; off >>= 1) {
        if (t < off) red[t] += red[t + off];
        __syncthreads();
    }
    if (t == 0) atomicAdd(out, red[0] * (1.0f / (float)BATCH));
}

extern "C" void kernel_launch(void* const* d_in, const int* in_sizes, int n_in,
                              void* d_out, int out_size, void* d_ws, size_t ws_size,
                              hipStream_t stream) {
    const float* x = (const float*)d_in[0];
    float* out = (float*)d_out;
    unsigned short* ws = (unsigned short*)d_ws;   // 2048*256*2 = 1 MiB used

    hist_kernel<<<dim3(BPB, BATCH), dim3(THREADS), 0, stream>>>(x, ws, out);
    entropy_kernel<<<dim3(BATCH), dim3(256), 0, stream>>>(ws, out);
}

// Round 9
// 22.222 us; speedup vs baseline: 1.0826x; 1.0826x over previous
//
#include <hip/hip_runtime.h>

// color_entropy_loss: x [32,3,512,512] f32 -> scalar f32
//   temp = (x*255).mean(axis=1); idx = clip(int(temp),0,255)
//   per-batch 256-bin histogram; hist[0] forced to H*W; hist += 1
//   prob = hist/(H*W+256); loss = mean_b( sum(prob*log(prob)) )
//
// R9: R7 (nt restored — A/B showed nt is +2us) + lane-parity dual LDS
// histograms per wave (8 copies, 8 KiB): isolates/halves same-address
// ds_add serialization (Irwin-Hall-peaked bins -> ~13 dup pairs/wave-instr).

typedef float vfloat4 __attribute__((ext_vector_type(4)));

constexpr int BATCH = 32;
constexpr int HW_ = 512 * 512;      // 262144
constexpr int BINS = 256;
constexpr int THREADS = 256;
constexpr int BPB = 64;                                   // blocks per batch -> 2048 blocks
constexpr int GROUPS_PER_BLOCK = (HW_ / 4) / BPB;         // 1024 float4 groups
constexpr int GPT = GROUPS_PER_BLOCK / THREADS;           // 4 groups per thread
constexpr int UNROLL = 4;
constexpr int PASSES = GPT / UNROLL;                      // 1
constexpr int NCOPY = 8;                                  // 4 waves x 2 (lane parity)

__global__ __launch_bounds__(THREADS) void hist_kernel(const float* __restrict__ x,
                                                       unsigned short* __restrict__ ws,
                                                       float* __restrict__ out) {
    // Per-(wave,lane-parity) privatized histograms: 8 * 256 * 4B = 8 KiB LDS
    __shared__ unsigned lh[NCOPY][BINS];
    const int t = threadIdx.x;
    const int copy = ((t >> 6) << 1) | (t & 1);
#pragma unroll
    for (int w = 0; w < NCOPY; ++w) lh[w][t] = 0u;
    if (blockIdx.x == 0 && blockIdx.y == 0 && t == 0) out[0] = 0.0f;  // K2 accumulates
    __syncthreads();

    const int b = blockIdx.y;
    const float* base = x + (size_t)b * 3 * HW_;
    const vfloat4* __restrict__ p0 = (const vfloat4*)(base);
    const vfloat4* __restrict__ p1 = (const vfloat4*)(base + HW_);
    const vfloat4* __restrict__ p2 = (const vfloat4*)(base + 2 * HW_);
    const int g0 = blockIdx.x * GROUPS_PER_BLOCK + t;

#pragma unroll
    for (int pass = 0; pass < PASSES; ++pass) {
        vfloat4 A[UNROLL], Bc[UNROLL], Cc[UNROLL];
#pragma unroll
        for (int u = 0; u < UNROLL; ++u) {
            int g = g0 + (pass * UNROLL + u) * THREADS;
            A[u]  = __builtin_nontemporal_load(p0 + g);   // streamed once, bypass L2
            Bc[u] = __builtin_nontemporal_load(p1 + g);
            Cc[u] = __builtin_nontemporal_load(p2 + g);
        }
#pragma unroll
        for (int u = 0; u < UNROLL; ++u) {
            // mean(x*255) = (a+b+c)*85 up to rounding; bin flips only at
            // integer boundaries (~1e-5 loss effect per flip, thr=0.103)
            float t0 = ((A[u].x + Bc[u].x) + Cc[u].x) * 85.0f;
            float t1 = ((A[u].y + Bc[u].y) + Cc[u].y) * 85.0f;
            float t2 = ((A[u].z + Bc[u].z) + Cc[u].z) * 85.0f;
            float t3 = ((A[u].w + Bc[u].w) + Cc[u].w) * 85.0f;
            int i0 = min(max((int)t0, 0), 255);   // trunc == astype(int32)
            int i1 = min(max((int)t1, 0), 255);
            int i2 = min(max((int)t2, 0), 255);
            int i3 = min(max((int)t3, 0), 255);
            atomicAdd(&lh[copy][i0], 1u);
            atomicAdd(&lh[copy][i1], 1u);
            atomicAdd(&lh[copy][i2], 1u);
            atomicAdd(&lh[copy][i3], 1u);
        }
    }
    __syncthreads();
    // Non-atomic per-block u16 partial store (max count 4096/block fits u16;
    // every slot written every call -> no zeroing needed)
    unsigned total = 0;
#pragma unroll
    for (int w = 0; w < NCOPY; ++w) total += lh[w][t];
    ws[((size_t)(b * BPB + blockIdx.x)) * BINS + t] = (unsigned short)total;
}

__global__ __launch_bounds__(256) void entropy_kernel(const unsigned short* __restrict__ ws,
                                                      float* __restrict__ out) {
    const int t = threadIdx.x;
    const int b = blockIdx.x;
    unsigned cnt = 0;
#pragma unroll 8
    for (int blk = 0; blk < BPB; ++blk)
        cnt += ws[((size_t)(b * BPB + blk)) * BINS + t];   // coalesced 128B/wave

    const float inv_np = 1.0f / (float)(HW_ + BINS);       // 1/262400
    // bin-0 quirk: counts[:,0] = H*W, then +1 smoothing on every bin
    float hist = (t == 0) ? ((float)HW_ + 1.0f) : ((float)cnt + 1.0f);
    float p = hist * inv_np;
    float v = p * logf(p);

    __shared__ float red[256];
    red[t] = v;
    __syncthreads();
    for (int off = 128; off > 0; off >>= 1) {
        if (t < off) red[t] += red[t + off];
        __syncthreads();
    }
    if (t == 0) atomicAdd(out, red[0] * (1.0f / (float)BATCH));
}

extern "C" void kernel_launch(void* const* d_in, const int* in_sizes, int n_in,
                              void* d_out, int out_size, void* d_ws, size_t ws_size,
                              hipStream_t stream) {
    const float* x = (const float*)d_in[0];
    float* out = (float*)d_out;
    unsigned short* ws = (unsigned short*)d_ws;   // 2048*256*2 = 1 MiB used

    hist_kernel<<<dim3(BPB, BATCH), dim3(THREADS), 0, stream>>>(x, ws, out);
    entropy_kernel<<<dim3(BATCH), dim3(256), 0, stream>>>(ws, out);
}

// Round 10
// 20.988 us; speedup vs baseline: 1.1462x; 1.0588x over previous
//
#include <hip/hip_runtime.h>

// color_entropy_loss: x [32,3,512,512] f32 -> scalar f32
//   temp = (x*255).mean(axis=1); idx = clip(int(temp),0,255)
//   per-batch 256-bin histogram; hist[0] forced to H*W; hist += 1
//   prob = hist/(H*W+256); loss = mean_b( sum(prob*log(prob)) )
//
// R10: nt + BPB=32 (2 passes/block -> load/compute overlap across passes,
// halved ramp/drain; R3-vs-R8 showed BPB32 +1.1us in no-nt regime) + u16
// partials + simple per-wave 4-copy LDS (R9 8-copy split was neutral).

typedef float vfloat4 __attribute__((ext_vector_type(4)));

constexpr int BATCH = 32;
constexpr int HW_ = 512 * 512;      // 262144
constexpr int BINS = 256;
constexpr int THREADS = 256;
constexpr int BPB = 32;                                   // blocks per batch -> 1024 blocks
constexpr int GROUPS_PER_BLOCK = (HW_ / 4) / BPB;         // 2048 float4 groups
constexpr int GPT = GROUPS_PER_BLOCK / THREADS;           // 8 groups per thread
constexpr int UNROLL = 4;
constexpr int PASSES = GPT / UNROLL;                      // 2

__global__ __launch_bounds__(THREADS) void hist_kernel(const float* __restrict__ x,
                                                       unsigned short* __restrict__ ws,
                                                       float* __restrict__ out) {
    // Per-wave privatized histograms: 4 waves * 256 bins * 4B = 4 KiB LDS
    __shared__ unsigned lh[4][BINS];
    const int t = threadIdx.x;
    const int wave = t >> 6;
#pragma unroll
    for (int w = 0; w < 4; ++w) lh[w][t] = 0u;
    if (blockIdx.x == 0 && blockIdx.y == 0 && t == 0) out[0] = 0.0f;  // K2 accumulates
    __syncthreads();

    const int b = blockIdx.y;
    const float* base = x + (size_t)b * 3 * HW_;
    const vfloat4* __restrict__ p0 = (const vfloat4*)(base);
    const vfloat4* __restrict__ p1 = (const vfloat4*)(base + HW_);
    const vfloat4* __restrict__ p2 = (const vfloat4*)(base + 2 * HW_);
    const int g0 = blockIdx.x * GROUPS_PER_BLOCK + t;

#pragma unroll
    for (int pass = 0; pass < PASSES; ++pass) {
        vfloat4 A[UNROLL], Bc[UNROLL], Cc[UNROLL];
#pragma unroll
        for (int u = 0; u < UNROLL; ++u) {
            int g = g0 + (pass * UNROLL + u) * THREADS;
            A[u]  = __builtin_nontemporal_load(p0 + g);   // streamed once, bypass L2
            Bc[u] = __builtin_nontemporal_load(p1 + g);
            Cc[u] = __builtin_nontemporal_load(p2 + g);
        }
#pragma unroll
        for (int u = 0; u < UNROLL; ++u) {
            // mean(x*255) = (a+b+c)*85 up to rounding; bin flips only at
            // integer boundaries (~1e-5 loss effect per flip, thr=0.103)
            float t0 = ((A[u].x + Bc[u].x) + Cc[u].x) * 85.0f;
            float t1 = ((A[u].y + Bc[u].y) + Cc[u].y) * 85.0f;
            float t2 = ((A[u].z + Bc[u].z) + Cc[u].z) * 85.0f;
            float t3 = ((A[u].w + Bc[u].w) + Cc[u].w) * 85.0f;
            int i0 = min(max((int)t0, 0), 255);   // trunc == astype(int32)
            int i1 = min(max((int)t1, 0), 255);
            int i2 = min(max((int)t2, 0), 255);
            int i3 = min(max((int)t3, 0), 255);
            atomicAdd(&lh[wave][i0], 1u);
            atomicAdd(&lh[wave][i1], 1u);
            atomicAdd(&lh[wave][i2], 1u);
            atomicAdd(&lh[wave][i3], 1u);
        }
    }
    __syncthreads();
    // Non-atomic per-block u16 partial store (max count 8192/block fits u16;
    // every slot written every call -> no zeroing needed)
    unsigned total = lh[0][t] + lh[1][t] + lh[2][t] + lh[3][t];
    ws[((size_t)(b * BPB + blockIdx.x)) * BINS + t] = (unsigned short)total;
}

__global__ __launch_bounds__(256) void entropy_kernel(const unsigned short* __restrict__ ws,
                                                      float* __restrict__ out) {
    const int t = threadIdx.x;
    const int b = blockIdx.x;
    unsigned cnt = 0;
#pragma unroll 8
    for (int blk = 0; blk < BPB; ++blk)
        cnt += ws[((size_t)(b * BPB + blk)) * BINS + t];   // coalesced 128B/wave

    const float inv_np = 1.0f / (float)(HW_ + BINS);       // 1/262400
    // bin-0 quirk: counts[:,0] = H*W, then +1 smoothing on every bin
    float hist = (t == 0) ? ((float)HW_ + 1.0f) : ((float)cnt + 1.0f);
    float p = hist * inv_np;
    float v = p * logf(p);

    __shared__ float red[256];
    red[t] = v;
    __syncthreads();
    for (int off = 128; off > 0; off >>= 1) {
        if (t < off) red[t] += red[t + off];
        __syncthreads();
    }
    if (t == 0) atomicAdd(out, red[0] * (1.0f / (float)BATCH));
}

extern "C" void kernel_launch(void* const* d_in, const int* in_sizes, int n_in,
                              void* d_out, int out_size, void* d_ws, size_t ws_size,
                              hipStream_t stream) {
    const float* x = (const float*)d_in[0];
    float* out = (float*)d_out;
    unsigned short* ws = (unsigned short*)d_ws;   // 1024*256*2 = 512 KiB used

    hist_kernel<<<dim3(BPB, BATCH), dim3(THREADS), 0, stream>>>(x, ws, out);
    entropy_kernel<<<dim3(BATCH), dim3(256), 0, stream>>>(ws, out);
}

// Round 11
// 20.948 us; speedup vs baseline: 1.1484x; 1.0019x over previous
//
#include <hip/hip_runtime.h>

// color_entropy_loss: x [32,3,512,512] f32 -> scalar f32
//   temp = (x*255).mean(axis=1); idx = clip(int(temp),0,255)
//   per-batch 256-bin histogram; hist[0] forced to H*W; hist += 1
//   prob = hist/(H*W+256); loss = mean_b( sum(prob*log(prob)) )
//
// R11: BPB 32->16 A/B (trend: fewer longer-lived blocks win in both nt and
// no-nt regimes -- steady-state cross-pass pipelining, less ramp/drain).
// Everything else identical to R10 (20.99 us).

typedef float vfloat4 __attribute__((ext_vector_type(4)));

constexpr int BATCH = 32;
constexpr int HW_ = 512 * 512;      // 262144
constexpr int BINS = 256;
constexpr int THREADS = 256;
constexpr int BPB = 16;                                   // blocks per batch -> 512 blocks
constexpr int GROUPS_PER_BLOCK = (HW_ / 4) / BPB;         // 4096 float4 groups
constexpr int GPT = GROUPS_PER_BLOCK / THREADS;           // 16 groups per thread
constexpr int UNROLL = 4;
constexpr int PASSES = GPT / UNROLL;                      // 4

__global__ __launch_bounds__(THREADS) void hist_kernel(const float* __restrict__ x,
                                                       unsigned short* __restrict__ ws,
                                                       float* __restrict__ out) {
    // Per-wave privatized histograms: 4 waves * 256 bins * 4B = 4 KiB LDS
    __shared__ unsigned lh[4][BINS];
    const int t = threadIdx.x;
    const int wave = t >> 6;
#pragma unroll
    for (int w = 0; w < 4; ++w) lh[w][t] = 0u;
    if (blockIdx.x == 0 && blockIdx.y == 0 && t == 0) out[0] = 0.0f;  // K2 accumulates
    __syncthreads();

    const int b = blockIdx.y;
    const float* base = x + (size_t)b * 3 * HW_;
    const vfloat4* __restrict__ p0 = (const vfloat4*)(base);
    const vfloat4* __restrict__ p1 = (const vfloat4*)(base + HW_);
    const vfloat4* __restrict__ p2 = (const vfloat4*)(base + 2 * HW_);
    const int g0 = blockIdx.x * GROUPS_PER_BLOCK + t;

#pragma unroll
    for (int pass = 0; pass < PASSES; ++pass) {
        vfloat4 A[UNROLL], Bc[UNROLL], Cc[UNROLL];
#pragma unroll
        for (int u = 0; u < UNROLL; ++u) {
            int g = g0 + (pass * UNROLL + u) * THREADS;
            A[u]  = __builtin_nontemporal_load(p0 + g);   // streamed once, bypass L2
            Bc[u] = __builtin_nontemporal_load(p1 + g);
            Cc[u] = __builtin_nontemporal_load(p2 + g);
        }
#pragma unroll
        for (int u = 0; u < UNROLL; ++u) {
            // mean(x*255) = (a+b+c)*85 up to rounding; bin flips only at
            // integer boundaries (~1e-5 loss effect per flip, thr=0.103)
            float t0 = ((A[u].x + Bc[u].x) + Cc[u].x) * 85.0f;
            float t1 = ((A[u].y + Bc[u].y) + Cc[u].y) * 85.0f;
            float t2 = ((A[u].z + Bc[u].z) + Cc[u].z) * 85.0f;
            float t3 = ((A[u].w + Bc[u].w) + Cc[u].w) * 85.0f;
            int i0 = min(max((int)t0, 0), 255);   // trunc == astype(int32)
            int i1 = min(max((int)t1, 0), 255);
            int i2 = min(max((int)t2, 0), 255);
            int i3 = min(max((int)t3, 0), 255);
            atomicAdd(&lh[wave][i0], 1u);
            atomicAdd(&lh[wave][i1], 1u);
            atomicAdd(&lh[wave][i2], 1u);
            atomicAdd(&lh[wave][i3], 1u);
        }
    }
    __syncthreads();
    // Non-atomic per-block u16 partial store (max count 16384/block fits u16;
    // every slot written every call -> no zeroing needed)
    unsigned total = lh[0][t] + lh[1][t] + lh[2][t] + lh[3][t];
    ws[((size_t)(b * BPB + blockIdx.x)) * BINS + t] = (unsigned short)total;
}

__global__ __launch_bounds__(256) void entropy_kernel(const unsigned short* __restrict__ ws,
                                                      float* __restrict__ out) {
    const int t = threadIdx.x;
    const int b = blockIdx.x;
    unsigned cnt = 0;
#pragma unroll 8
    for (int blk = 0; blk < BPB; ++blk)
        cnt += ws[((size_t)(b * BPB + blk)) * BINS + t];   // coalesced 128B/wave

    const float inv_np = 1.0f / (float)(HW_ + BINS);       // 1/262400
    // bin-0 quirk: counts[:,0] = H*W, then +1 smoothing on every bin
    float hist = (t == 0) ? ((float)HW_ + 1.0f) : ((float)cnt + 1.0f);
    float p = hist * inv_np;
    float v = p * logf(p);

    __shared__ float red[256];
    red[t] = v;
    __syncthreads();
    for (int off = 128; off > 0; off >>= 1) {
        if (t < off) red[t] += red[t + off];
        __syncthreads();
    }
    if (t == 0) atomicAdd(out, red[0] * (1.0f / (float)BATCH));
}

extern "C" void kernel_launch(void* const* d_in, const int* in_sizes, int n_in,
                              void* d_out, int out_size, void* d_ws, size_t ws_size,
                              hipStream_t stream) {
    const float* x = (const float*)d_in[0];
    float* out = (float*)d_out;
    unsigned short* ws = (unsigned short*)d_ws;   // 512*256*2 = 256 KiB used

    hist_kernel<<<dim3(BPB, BATCH), dim3(THREADS), 0, stream>>>(x, ws, out);
    entropy_kernel<<<dim3(BATCH), dim3(256), 0, stream>>>(ws, out);
}